// Round 6
// baseline (214.156 us; speedup 1.0000x reference)
//
#include <hip/hip_runtime.h>
#include <hip/hip_bf16.h>

#define N_NODES 16000
#define IN_F 128
#define HID 64
#define BATCH 32
#define NPAIR 128
#define DRES 100
#define NCLS 10

// workspace layout (float offsets)
#define NF_OFF     0
#define WT1_OFF    16000                     // [2 ic][25 tap][16 oc]
#define WT2_OFF    (16000 + 800)             // [16 ic][25 tap][32 oc]
#define INV_OFF    (16000 + 800 + 12800)     // [64] per-(b,c) 1/max
#define IMGSP_OFF  (INV_OFF + 64)            // [32][2][104][104] padded
#define POOL1P_OFF (IMGSP_OFF + 32*2*104*104)   // [32][16][54][56] padded
#define POOL2_OFF  (POOL1P_OFF + 32*16*54*56)   // [32][32][25][25]
#define ZERO_N4    ((32*2*104*104 + 32*16*54*56) / 4)

// float2 patch element access (compile-time index under full unroll)
#define PV(P, r, c) (((c) & 1) ? P[(r)*3 + ((c)>>1)].y : P[(r)*3 + ((c)>>1)].x)

// ---------------- Kernel I: weight transpose + zero padded buffers ----------------
__global__ __launch_bounds__(256) void k_init(const float* __restrict__ c1w,
    const float* __restrict__ c2w, float* __restrict__ wT1, float* __restrict__ wT2,
    float* __restrict__ zbase)
{
    int bx = blockIdx.x, t = threadIdx.x;
    if (bx == 0) {
        for (int i = t; i < 800; i += 256) {
            int ic = i / 400, tap = (i / 16) % 25, oc = i % 16;
            wT1[i] = c1w[(oc * 2 + ic) * 25 + tap];
        }
    } else if (bx == 1) {
        for (int i = t; i < 12800; i += 256) {
            int ic = i / 800, tap = (i / 32) % 25, oc = i % 32;
            wT2[i] = c2w[(oc * 16 + ic) * 25 + tap];
        }
    } else {
        int i = (bx - 2) * 256 + t;
        if (i < ZERO_N4) ((float4*)zbase)[i] = make_float4(0.f, 0.f, 0.f, 0.f);
    }
}

// ---------------- Kernel A: node filtration MLP (4 nodes per wave) ----------------
__global__ __launch_bounds__(256) void k_filt(const float* __restrict__ x,
    const float* __restrict__ w1, const float* __restrict__ b1,
    const float* __restrict__ w2, const float* __restrict__ b2,
    float* __restrict__ nf, float* __restrict__ out_nf)
{
    int t = threadIdx.x, wave = t >> 6, lane = t & 63;
    int n0 = blockIdx.x * 16 + wave * 4;
    const float* x0 = x + (size_t)n0 * IN_F;
    float a0 = 0.f, a1 = 0.f, a2 = 0.f, a3 = 0.f;
    #pragma unroll 4
    for (int k = 0; k < IN_F; ++k) {
        float wv = w1[k * HID + lane];
        a0 = fmaf(x0[k], wv, a0);
        a1 = fmaf(x0[k + IN_F], wv, a1);
        a2 = fmaf(x0[k + 2 * IN_F], wv, a2);
        a3 = fmaf(x0[k + 3 * IN_F], wv, a3);
    }
    float bb = b1[lane], w2v = w2[lane];
    float p0 = fmaxf(a0 + bb, 0.f) * w2v;
    float p1 = fmaxf(a1 + bb, 0.f) * w2v;
    float p2 = fmaxf(a2 + bb, 0.f) * w2v;
    float p3 = fmaxf(a3 + bb, 0.f) * w2v;
    #pragma unroll
    for (int off = 32; off > 0; off >>= 1) {
        p0 += __shfl_xor(p0, off, 64);
        p1 += __shfl_xor(p1, off, 64);
        p2 += __shfl_xor(p2, off, 64);
        p3 += __shfl_xor(p3, off, 64);
    }
    if (lane == 0) {
        float bv = b2[0];
        float f0 = 1.f / (1.f + expf(-(p0 + bv)));
        float f1 = 1.f / (1.f + expf(-(p1 + bv)));
        float f2 = 1.f / (1.f + expf(-(p2 + bv)));
        float f3 = 1.f / (1.f + expf(-(p3 + bv)));
        nf[n0] = f0; nf[n0 + 1] = f1; nf[n0 + 2] = f2; nf[n0 + 3] = f3;
        out_nf[n0] = f0; out_nf[n0 + 1] = f1; out_nf[n0 + 2] = f2; out_nf[n0 + 3] = f3;
    }
}

// ---------------- Kernel B: persistence image partial accumulate ----------------
// 256 blocks: (img, quarter). 4 quarter-blocks of an img share g%8 -> same XCD L2.
__global__ __launch_bounds__(256) void k_pimg(const float* __restrict__ nf,
    const int* __restrict__ pi0, const int* __restrict__ pi1,
    float* __restrict__ imgs_p)
{
    int g = blockIdx.x;
    int img = (g & 7) * 8 + ((g >> 3) & 7);
    int q = g >> 6;
    int b = img >> 1, c = img & 1;
    const int* pi = c ? pi1 : pi0;
    __shared__ float sb[32], sp[32];
    int t = threadIdx.x;
    if (t < 32) {
        int p = q * 32 + t;
        int i0 = pi[(b * NPAIR + p) * 2 + 0];
        int i1 = pi[(b * NPAIR + p) * 2 + 1];
        float f0 = nf[i0], f1 = nf[i1];
        sb[t] = f0;
        sp[t] = f1 - f0;
    }
    __syncthreads();
    if (t >= 169) return;
    int ti = t / 13, tj = t % 13;
    float ci[8], cj[8];
    #pragma unroll
    for (int r = 0; r < 8; ++r) {
        ci[r] = (float)(ti + 13 * r) * 0.01f;
        cj[r] = (float)(tj + 13 * r) * 0.01f;
    }
    float acc[8][8];
    #pragma unroll
    for (int r = 0; r < 8; ++r)
        #pragma unroll
        for (int s = 0; s < 8; ++s) acc[r][s] = 0.f;
    for (int p = 0; p < 32; ++p) {
        float bb = sb[p], pp = sp[p];
        float eb[8], ep[8];
        #pragma unroll
        for (int r = 0; r < 8; ++r) { float d = bb - ci[r]; eb[r] = __expf(-d * d); }
        #pragma unroll
        for (int s = 0; s < 8; ++s) { float d = pp - cj[s]; ep[s] = __expf(-d * d); }
        #pragma unroll
        for (int r = 0; r < 8; ++r)
            #pragma unroll
            for (int s = 0; s < 8; ++s)
                acc[r][s] = fmaf(eb[r], ep[s], acc[r][s]);
    }
    float* dst = imgs_p + (size_t)img * 10816 + 2 * 104 + 2;
    #pragma unroll
    for (int r = 0; r < 8; ++r) {
        int i = ti + 13 * r;
        if (i < DRES) {
            #pragma unroll
            for (int s = 0; s < 8; ++s) {
                int j = tj + 13 * s;
                if (j < DRES) atomicAdd(&dst[i * 104 + j], acc[r][s]);
            }
        }
    }
}

// ---------------- Kernel M: per-image max -> inv ----------------
__global__ __launch_bounds__(256) void k_pmax(const float* __restrict__ imgs_p,
    float* __restrict__ inv)
{
    int img = blockIdx.x;
    const float4* src = (const float4*)(imgs_p + (size_t)img * 10816);
    int t = threadIdx.x;
    float m = 0.f;
    for (int k = t; k < 2704; k += 256) {
        float4 v = src[k];
        m = fmaxf(m, fmaxf(fmaxf(v.x, v.y), fmaxf(v.z, v.w)));
    }
    #pragma unroll
    for (int off = 32; off > 0; off >>= 1)
        m = fmaxf(m, __shfl_xor(m, off, 64));
    __shared__ float wm[4];
    if ((t & 63) == 0) wm[t >> 6] = m;
    __syncthreads();
    if (t == 0) {
        float bm = fmaxf(fmaxf(wm[0], wm[1]), fmaxf(wm[2], wm[3]));
        inv[img] = 1.f / bm;
    }
}

// ---------------- Kernel C: conv1 + relu + maxpool2 ----------------
// 1280 blocks: (b, ocg in 4, rowgroup in 10). 250 active threads = 50 ow x 5 rows.
__global__ __launch_bounds__(256) void k_conv1(const float* __restrict__ imgs_p,
    const float* __restrict__ wT1, const float* __restrict__ cb,
    const float* __restrict__ inv, float* __restrict__ pool1p)
{
    int g = blockIdx.x;
    int b = (g & 7) * 4 + ((g >> 3) & 3);
    int ocg = (g >> 5) & 3;
    int rg = g >> 7;
    int t = threadIdx.x;
    if (t >= 250) return;
    int ow = t % 50, oh = rg * 5 + t / 50;

    float2 PA[18], PB[18];
    {
        const float* bs = imgs_p + (size_t)(b * 2 + 0) * 10816 + (2 * oh) * 104 + 2 * ow;
        #pragma unroll
        for (int r = 0; r < 6; ++r) {
            const float* rp = bs + r * 104;
            PA[r * 3 + 0] = *(const float2*)rp;
            PA[r * 3 + 1] = *(const float2*)(rp + 2);
            PA[r * 3 + 2] = *(const float2*)(rp + 4);
        }
        const float* bs1 = bs + 10816;
        #pragma unroll
        for (int r = 0; r < 6; ++r) {
            const float* rp = bs1 + r * 104;
            PB[r * 3 + 0] = *(const float2*)rp;
            PB[r * 3 + 1] = *(const float2*)(rp + 2);
            PB[r * 3 + 2] = *(const float2*)(rp + 4);
        }
    }
    float acc0[4][2][2] = {}, acc1[4][2][2] = {};
    const float* w0 = wT1 + ocg * 4;
    const float* w1r = wT1 + 400 + ocg * 4;
    #pragma unroll
    for (int kh = 0; kh < 5; ++kh)
        #pragma unroll
        for (int kw = 0; kw < 5; ++kw) {
            float4 wa = *(const float4*)(w0 + (kh * 5 + kw) * 16);
            float4 wb = *(const float4*)(w1r + (kh * 5 + kw) * 16);
            #pragma unroll
            for (int j = 0; j < 2; ++j)
                #pragma unroll
                for (int i = 0; i < 2; ++i) {
                    float va = PV(PA, kh + j, kw + i);
                    float vb = PV(PB, kh + j, kw + i);
                    acc0[0][j][i] = fmaf(va, wa.x, acc0[0][j][i]);
                    acc0[1][j][i] = fmaf(va, wa.y, acc0[1][j][i]);
                    acc0[2][j][i] = fmaf(va, wa.z, acc0[2][j][i]);
                    acc0[3][j][i] = fmaf(va, wa.w, acc0[3][j][i]);
                    acc1[0][j][i] = fmaf(vb, wb.x, acc1[0][j][i]);
                    acc1[1][j][i] = fmaf(vb, wb.y, acc1[1][j][i]);
                    acc1[2][j][i] = fmaf(vb, wb.z, acc1[2][j][i]);
                    acc1[3][j][i] = fmaf(vb, wb.w, acc1[3][j][i]);
                }
        }
    float sc0 = inv[b * 2 + 0], sc1 = inv[b * 2 + 1];
    float4 bias4 = *(const float4*)(cb + ocg * 4);
    float bv[4] = {bias4.x, bias4.y, bias4.z, bias4.w};
    #pragma unroll
    for (int o = 0; o < 4; ++o) {
        float v00 = fmaf(sc1, acc1[o][0][0], sc0 * acc0[o][0][0]);
        float v01 = fmaf(sc1, acc1[o][0][1], sc0 * acc0[o][0][1]);
        float v10 = fmaf(sc1, acc1[o][1][0], sc0 * acc0[o][1][0]);
        float v11 = fmaf(sc1, acc1[o][1][1], sc0 * acc0[o][1][1]);
        float m = fmaxf(fmaxf(v00, v01), fmaxf(v10, v11));
        pool1p[((size_t)(b * 16 + ocg * 4 + o) * 54 + oh + 2) * 56 + ow + 2] =
            fmaxf(m + bv[o], 0.f);
    }
}

// ---------------- Kernel D: conv2 + relu + maxpool2 ----------------
// 512 blocks (b, ocg in 16), 640 threads (625 active), thread = 2 oc x 1 pooled output.
// 2 blocks/CU -> 5 waves/SIMD; launch_bounds(640,5) caps VGPR at 102.
__global__ __launch_bounds__(640, 5) void k_conv2(const float* __restrict__ pool1p,
    const float* __restrict__ wT2, const float* __restrict__ cb,
    float* __restrict__ pool2)
{
    int g = blockIdx.x;
    int b = (g & 7) * 4 + ((g >> 3) & 3);
    int ocg = g >> 5;          // 0..15, 2 oc each
    int t = threadIdx.x;
    if (t >= 625) return;
    int py = t / 25, px = t % 25;
    float acc[2][2][2] = {};
    float2 PA[18], PB[18];

    auto LOADP = [&](float2 (&P)[18], int ic) {
        const float* bs = pool1p + (size_t)(b * 16 + ic) * 3024 + (2 * py) * 56 + 2 * px;
        #pragma unroll
        for (int r = 0; r < 6; ++r) {
            const float* rp = bs + r * 56;
            P[r * 3 + 0] = *(const float2*)rp;
            P[r * 3 + 1] = *(const float2*)(rp + 2);
            P[r * 3 + 2] = *(const float2*)(rp + 4);
        }
    };
    auto FMAIC = [&](float2 (&P)[18], int ic) {
        const float* wrow = wT2 + ic * 800 + ocg * 2;
        #pragma unroll
        for (int kh = 0; kh < 5; ++kh)
            #pragma unroll
            for (int kw = 0; kw < 5; ++kw) {
                float2 wv = *(const float2*)(wrow + (kh * 5 + kw) * 32);
                #pragma unroll
                for (int j = 0; j < 2; ++j)
                    #pragma unroll
                    for (int i = 0; i < 2; ++i) {
                        float v = PV(P, kh + j, kw + i);
                        acc[0][j][i] = fmaf(v, wv.x, acc[0][j][i]);
                        acc[1][j][i] = fmaf(v, wv.y, acc[1][j][i]);
                    }
            }
    };

    LOADP(PA, 0);
    #pragma unroll 1
    for (int ic = 0; ic < 16; ic += 2) {
        LOADP(PB, ic + 1);
        FMAIC(PA, ic);
        if (ic + 2 < 16) LOADP(PA, ic + 2);
        FMAIC(PB, ic + 1);
    }

    float2 bias2 = *(const float2*)(cb + ocg * 2);
    float bv[2] = {bias2.x, bias2.y};
    #pragma unroll
    for (int o = 0; o < 2; ++o) {
        float m = fmaxf(fmaxf(acc[o][0][0], acc[o][0][1]),
                        fmaxf(acc[o][1][0], acc[o][1][1]));
        pool2[((size_t)(b * 32 + ocg * 2 + o) * 25 + py) * 25 + px] =
            fmaxf(m + bv[o], 0.f);
    }
}

// ---------------- Kernel E: final linear (float4) ----------------
__global__ __launch_bounds__(256) void k_fc(const float* __restrict__ pool2,
    const float* __restrict__ oww, const float* __restrict__ ob,
    float* __restrict__ yhat)
{
    int cls = blockIdx.x / BATCH, b = blockIdx.x % BATCH;
    int t = threadIdx.x;
    const float4* y = (const float4*)(pool2 + (size_t)b * 20000);
    const float4* w = (const float4*)(oww + (size_t)cls * 20000);
    float acc = 0.f;
    for (int k = t; k < 5000; k += 256) {
        float4 a = y[k], ww = w[k];
        acc += a.x * ww.x + a.y * ww.y + a.z * ww.z + a.w * ww.w;
    }
    #pragma unroll
    for (int off = 32; off > 0; off >>= 1)
        acc += __shfl_xor(acc, off, 64);
    __shared__ float part[4];
    if ((t & 63) == 0) part[t >> 6] = acc;
    __syncthreads();
    if (t == 0)
        yhat[b * NCLS + cls] = part[0] + part[1] + part[2] + part[3] + ob[cls];
}

extern "C" void kernel_launch(void* const* d_in, const int* in_sizes, int n_in,
                              void* d_out, int out_size, void* d_ws, size_t ws_size,
                              hipStream_t stream)
{
    const float* x   = (const float*)d_in[0];
    const int*   pi0 = (const int*)d_in[1];
    const int*   pi1 = (const int*)d_in[2];
    const float* w1  = (const float*)d_in[3];
    const float* b1  = (const float*)d_in[4];
    const float* w2  = (const float*)d_in[5];
    const float* b2  = (const float*)d_in[6];
    const float* c1w = (const float*)d_in[7];
    const float* c1b = (const float*)d_in[8];
    const float* c2w = (const float*)d_in[9];
    const float* c2b = (const float*)d_in[10];
    const float* oww = (const float*)d_in[11];
    const float* owb = (const float*)d_in[12];
    float* out = (float*)d_out;
    float* ws = (float*)d_ws;

    float* nf     = ws + NF_OFF;
    float* wT1    = ws + WT1_OFF;
    float* wT2    = ws + WT2_OFF;
    float* inv    = ws + INV_OFF;
    float* imgs_p = ws + IMGSP_OFF;
    float* pool1p = ws + POOL1P_OFF;
    float* pool2  = ws + POOL2_OFF;

    k_init <<<2 + (ZERO_N4 + 255) / 256, 256, 0, stream>>>(c1w, c2w, wT1, wT2, imgs_p);
    k_filt <<<1000, 256, 0, stream>>>(x, w1, b1, w2, b2, nf, out + BATCH * NCLS);
    k_pimg <<<256, 256, 0, stream>>>(nf, pi0, pi1, imgs_p);
    k_pmax <<<64, 256, 0, stream>>>(imgs_p, inv);
    k_conv1<<<1280, 256, 0, stream>>>(imgs_p, wT1, c1b, inv, pool1p);
    k_conv2<<<512, 640, 0, stream>>>(pool1p, wT2, c2b, pool2);
    k_fc   <<<BATCH * NCLS, 256, 0, stream>>>(pool2, oww, owb, out);
}

// Round 7
// 174.044 us; speedup vs baseline: 1.2305x; 1.2305x over previous
//
#include <hip/hip_runtime.h>
#include <hip/hip_bf16.h>

#define N_NODES 16000
#define IN_F 128
#define HID 64
#define BATCH 32
#define NPAIR 128
#define DRES 100
#define NCLS 10

// workspace layout (float offsets)
#define NF_OFF     0
#define WT1_OFF    16000                     // [2 ic][25 tap][16 oc]
#define WT2_OFF    (16000 + 800)             // [16 ic][25 tap][32 oc]
#define INV_OFF    (16000 + 800 + 12800)     // [64] per-(b,c) 1/max
#define IMGSP_OFF  (INV_OFF + 64)            // [32][2][104][104] padded
#define POOL1P_OFF (IMGSP_OFF + 32*2*104*104)   // [32][16][54][56] padded
#define POOL2_OFF  (POOL1P_OFF + 32*16*54*56)   // [32][32][25][25]
#define ZERO_N4    ((32*2*104*104 + 32*16*54*56) / 4)

// float2 patch element access (compile-time index under full unroll)
#define PV(P, r, c) (((c) & 1) ? P[(r)*3 + ((c)>>1)].y : P[(r)*3 + ((c)>>1)].x)

// ---------------- Kernel I: weight transpose + zero padded buffers ----------------
__global__ __launch_bounds__(256) void k_init(const float* __restrict__ c1w,
    const float* __restrict__ c2w, float* __restrict__ wT1, float* __restrict__ wT2,
    float* __restrict__ zbase)
{
    int bx = blockIdx.x, t = threadIdx.x;
    if (bx == 0) {
        for (int i = t; i < 800; i += 256) {
            int ic = i / 400, tap = (i / 16) % 25, oc = i % 16;
            wT1[i] = c1w[(oc * 2 + ic) * 25 + tap];
        }
    } else if (bx == 1) {
        for (int i = t; i < 12800; i += 256) {
            int ic = i / 800, tap = (i / 32) % 25, oc = i % 32;
            wT2[i] = c2w[(oc * 16 + ic) * 25 + tap];
        }
    } else {
        int i = (bx - 2) * 256 + t;
        if (i < ZERO_N4) ((float4*)zbase)[i] = make_float4(0.f, 0.f, 0.f, 0.f);
    }
}

// ---------------- Kernel A: node filtration MLP (4 nodes per wave) ----------------
__global__ __launch_bounds__(256) void k_filt(const float* __restrict__ x,
    const float* __restrict__ w1, const float* __restrict__ b1,
    const float* __restrict__ w2, const float* __restrict__ b2,
    float* __restrict__ nf, float* __restrict__ out_nf)
{
    int t = threadIdx.x, wave = t >> 6, lane = t & 63;
    int n0 = blockIdx.x * 16 + wave * 4;
    const float* x0 = x + (size_t)n0 * IN_F;
    float a0 = 0.f, a1 = 0.f, a2 = 0.f, a3 = 0.f;
    #pragma unroll 4
    for (int k = 0; k < IN_F; ++k) {
        float wv = w1[k * HID + lane];
        a0 = fmaf(x0[k], wv, a0);
        a1 = fmaf(x0[k + IN_F], wv, a1);
        a2 = fmaf(x0[k + 2 * IN_F], wv, a2);
        a3 = fmaf(x0[k + 3 * IN_F], wv, a3);
    }
    float bb = b1[lane], w2v = w2[lane];
    float p0 = fmaxf(a0 + bb, 0.f) * w2v;
    float p1 = fmaxf(a1 + bb, 0.f) * w2v;
    float p2 = fmaxf(a2 + bb, 0.f) * w2v;
    float p3 = fmaxf(a3 + bb, 0.f) * w2v;
    #pragma unroll
    for (int off = 32; off > 0; off >>= 1) {
        p0 += __shfl_xor(p0, off, 64);
        p1 += __shfl_xor(p1, off, 64);
        p2 += __shfl_xor(p2, off, 64);
        p3 += __shfl_xor(p3, off, 64);
    }
    if (lane == 0) {
        float bv = b2[0];
        float f0 = 1.f / (1.f + expf(-(p0 + bv)));
        float f1 = 1.f / (1.f + expf(-(p1 + bv)));
        float f2 = 1.f / (1.f + expf(-(p2 + bv)));
        float f3 = 1.f / (1.f + expf(-(p3 + bv)));
        nf[n0] = f0; nf[n0 + 1] = f1; nf[n0 + 2] = f2; nf[n0 + 3] = f3;
        out_nf[n0] = f0; out_nf[n0 + 1] = f1; out_nf[n0 + 2] = f2; out_nf[n0 + 3] = f3;
    }
}

// ---------------- Kernel B: persistence image partial accumulate ----------------
// 256 blocks: (img, quarter). 4 quarter-blocks of an img share g%8 -> same XCD L2.
__global__ __launch_bounds__(256) void k_pimg(const float* __restrict__ nf,
    const int* __restrict__ pi0, const int* __restrict__ pi1,
    float* __restrict__ imgs_p)
{
    int g = blockIdx.x;
    int img = (g & 7) * 8 + ((g >> 3) & 7);
    int q = g >> 6;
    int b = img >> 1, c = img & 1;
    const int* pi = c ? pi1 : pi0;
    __shared__ float sb[32], sp[32];
    int t = threadIdx.x;
    if (t < 32) {
        int p = q * 32 + t;
        int i0 = pi[(b * NPAIR + p) * 2 + 0];
        int i1 = pi[(b * NPAIR + p) * 2 + 1];
        float f0 = nf[i0], f1 = nf[i1];
        sb[t] = f0;
        sp[t] = f1 - f0;
    }
    __syncthreads();
    if (t >= 169) return;
    int ti = t / 13, tj = t % 13;
    float ci[8], cj[8];
    #pragma unroll
    for (int r = 0; r < 8; ++r) {
        ci[r] = (float)(ti + 13 * r) * 0.01f;
        cj[r] = (float)(tj + 13 * r) * 0.01f;
    }
    float acc[8][8];
    #pragma unroll
    for (int r = 0; r < 8; ++r)
        #pragma unroll
        for (int s = 0; s < 8; ++s) acc[r][s] = 0.f;
    for (int p = 0; p < 32; ++p) {
        float bb = sb[p], pp = sp[p];
        float eb[8], ep[8];
        #pragma unroll
        for (int r = 0; r < 8; ++r) { float d = bb - ci[r]; eb[r] = __expf(-d * d); }
        #pragma unroll
        for (int s = 0; s < 8; ++s) { float d = pp - cj[s]; ep[s] = __expf(-d * d); }
        #pragma unroll
        for (int r = 0; r < 8; ++r)
            #pragma unroll
            for (int s = 0; s < 8; ++s)
                acc[r][s] = fmaf(eb[r], ep[s], acc[r][s]);
    }
    float* dst = imgs_p + (size_t)img * 10816 + 2 * 104 + 2;
    #pragma unroll
    for (int r = 0; r < 8; ++r) {
        int i = ti + 13 * r;
        if (i < DRES) {
            #pragma unroll
            for (int s = 0; s < 8; ++s) {
                int j = tj + 13 * s;
                if (j < DRES) atomicAdd(&dst[i * 104 + j], acc[r][s]);
            }
        }
    }
}

// ---------------- Kernel M: per-image max -> inv ----------------
__global__ __launch_bounds__(256) void k_pmax(const float* __restrict__ imgs_p,
    float* __restrict__ inv)
{
    int img = blockIdx.x;
    const float4* src = (const float4*)(imgs_p + (size_t)img * 10816);
    int t = threadIdx.x;
    float m = 0.f;
    for (int k = t; k < 2704; k += 256) {
        float4 v = src[k];
        m = fmaxf(m, fmaxf(fmaxf(v.x, v.y), fmaxf(v.z, v.w)));
    }
    #pragma unroll
    for (int off = 32; off > 0; off >>= 1)
        m = fmaxf(m, __shfl_xor(m, off, 64));
    __shared__ float wm[4];
    if ((t & 63) == 0) wm[t >> 6] = m;
    __syncthreads();
    if (t == 0) {
        float bm = fmaxf(fmaxf(wm[0], wm[1]), fmaxf(wm[2], wm[3]));
        inv[img] = 1.f / bm;
    }
}

// ---------------- Kernel C: conv1 + relu + maxpool2 ----------------
// 1280 blocks: (b, ocg in 4, rowgroup in 10). 250 active threads = 50 ow x 5 rows.
__global__ __launch_bounds__(256) void k_conv1(const float* __restrict__ imgs_p,
    const float* __restrict__ wT1, const float* __restrict__ cb,
    const float* __restrict__ inv, float* __restrict__ pool1p)
{
    int g = blockIdx.x;
    int b = (g & 7) * 4 + ((g >> 3) & 3);
    int ocg = (g >> 5) & 3;
    int rg = g >> 7;
    int t = threadIdx.x;
    if (t >= 250) return;
    int ow = t % 50, oh = rg * 5 + t / 50;

    float2 PA[18], PB[18];
    {
        const float* bs = imgs_p + (size_t)(b * 2 + 0) * 10816 + (2 * oh) * 104 + 2 * ow;
        #pragma unroll
        for (int r = 0; r < 6; ++r) {
            const float* rp = bs + r * 104;
            PA[r * 3 + 0] = *(const float2*)rp;
            PA[r * 3 + 1] = *(const float2*)(rp + 2);
            PA[r * 3 + 2] = *(const float2*)(rp + 4);
        }
        const float* bs1 = bs + 10816;
        #pragma unroll
        for (int r = 0; r < 6; ++r) {
            const float* rp = bs1 + r * 104;
            PB[r * 3 + 0] = *(const float2*)rp;
            PB[r * 3 + 1] = *(const float2*)(rp + 2);
            PB[r * 3 + 2] = *(const float2*)(rp + 4);
        }
    }
    float acc0[4][2][2] = {}, acc1[4][2][2] = {};
    const float* w0 = wT1 + ocg * 4;
    const float* w1r = wT1 + 400 + ocg * 4;
    #pragma unroll
    for (int kh = 0; kh < 5; ++kh)
        #pragma unroll
        for (int kw = 0; kw < 5; ++kw) {
            float4 wa = *(const float4*)(w0 + (kh * 5 + kw) * 16);
            float4 wb = *(const float4*)(w1r + (kh * 5 + kw) * 16);
            #pragma unroll
            for (int j = 0; j < 2; ++j)
                #pragma unroll
                for (int i = 0; i < 2; ++i) {
                    float va = PV(PA, kh + j, kw + i);
                    float vb = PV(PB, kh + j, kw + i);
                    acc0[0][j][i] = fmaf(va, wa.x, acc0[0][j][i]);
                    acc0[1][j][i] = fmaf(va, wa.y, acc0[1][j][i]);
                    acc0[2][j][i] = fmaf(va, wa.z, acc0[2][j][i]);
                    acc0[3][j][i] = fmaf(va, wa.w, acc0[3][j][i]);
                    acc1[0][j][i] = fmaf(vb, wb.x, acc1[0][j][i]);
                    acc1[1][j][i] = fmaf(vb, wb.y, acc1[1][j][i]);
                    acc1[2][j][i] = fmaf(vb, wb.z, acc1[2][j][i]);
                    acc1[3][j][i] = fmaf(vb, wb.w, acc1[3][j][i]);
                }
        }
    float sc0 = inv[b * 2 + 0], sc1 = inv[b * 2 + 1];
    float4 bias4 = *(const float4*)(cb + ocg * 4);
    float bv[4] = {bias4.x, bias4.y, bias4.z, bias4.w};
    #pragma unroll
    for (int o = 0; o < 4; ++o) {
        float v00 = fmaf(sc1, acc1[o][0][0], sc0 * acc0[o][0][0]);
        float v01 = fmaf(sc1, acc1[o][0][1], sc0 * acc0[o][0][1]);
        float v10 = fmaf(sc1, acc1[o][1][0], sc0 * acc0[o][1][0]);
        float v11 = fmaf(sc1, acc1[o][1][1], sc0 * acc0[o][1][1]);
        float m = fmaxf(fmaxf(v00, v01), fmaxf(v10, v11));
        pool1p[((size_t)(b * 16 + ocg * 4 + o) * 54 + oh + 2) * 56 + ow + 2] =
            fmaxf(m + bv[o], 0.f);
    }
}

// ---------------- Kernel D: conv2 + relu + maxpool2 ----------------
// 1024 blocks: (b, ocg in 16, half q in 2). 320 threads, thread = 2 oc x 1 pooled
// output o = q*320 + t (o < 625). NO min-waves launch bound: round-6's (640,5)
// capped VGPR at 48 and spilled PA/PB to scratch (292 MB writes). Plain bound
// keeps ~96 VGPR -> 4 blocks/CU = 20 waves/CU.
__global__ __launch_bounds__(320) void k_conv2(const float* __restrict__ pool1p,
    const float* __restrict__ wT2, const float* __restrict__ cb,
    float* __restrict__ pool2)
{
    int g = blockIdx.x;
    int b = (g & 7) * 4 + ((g >> 3) & 3);
    int rest = g >> 5;
    int ocg = rest & 15;       // 0..15, 2 oc each
    int q = rest >> 4;         // 0..1
    int o = q * 320 + threadIdx.x;
    if (o >= 625) return;
    int py = o / 25, px = o % 25;
    float acc[2][2][2] = {};
    float2 PA[18], PB[18];

    auto LOADP = [&](float2 (&P)[18], int ic) {
        const float* bs = pool1p + (size_t)(b * 16 + ic) * 3024 + (2 * py) * 56 + 2 * px;
        #pragma unroll
        for (int r = 0; r < 6; ++r) {
            const float* rp = bs + r * 56;
            P[r * 3 + 0] = *(const float2*)rp;
            P[r * 3 + 1] = *(const float2*)(rp + 2);
            P[r * 3 + 2] = *(const float2*)(rp + 4);
        }
    };
    auto FMAIC = [&](float2 (&P)[18], int ic) {
        const float* wrow = wT2 + ic * 800 + ocg * 2;
        #pragma unroll
        for (int kh = 0; kh < 5; ++kh)
            #pragma unroll
            for (int kw = 0; kw < 5; ++kw) {
                float2 wv = *(const float2*)(wrow + (kh * 5 + kw) * 32);
                #pragma unroll
                for (int j = 0; j < 2; ++j)
                    #pragma unroll
                    for (int i = 0; i < 2; ++i) {
                        float v = PV(P, kh + j, kw + i);
                        acc[0][j][i] = fmaf(v, wv.x, acc[0][j][i]);
                        acc[1][j][i] = fmaf(v, wv.y, acc[1][j][i]);
                    }
            }
    };

    LOADP(PA, 0);
    #pragma unroll 1
    for (int ic = 0; ic < 16; ic += 2) {
        LOADP(PB, ic + 1);
        FMAIC(PA, ic);
        if (ic + 2 < 16) LOADP(PA, ic + 2);
        FMAIC(PB, ic + 1);
    }

    float2 bias2 = *(const float2*)(cb + ocg * 2);
    float bv[2] = {bias2.x, bias2.y};
    #pragma unroll
    for (int oo = 0; oo < 2; ++oo) {
        float m = fmaxf(fmaxf(acc[oo][0][0], acc[oo][0][1]),
                        fmaxf(acc[oo][1][0], acc[oo][1][1]));
        pool2[((size_t)(b * 32 + ocg * 2 + oo) * 25 + py) * 25 + px] =
            fmaxf(m + bv[oo], 0.f);
    }
}

// ---------------- Kernel E: final linear (float4) ----------------
__global__ __launch_bounds__(256) void k_fc(const float* __restrict__ pool2,
    const float* __restrict__ oww, const float* __restrict__ ob,
    float* __restrict__ yhat)
{
    int cls = blockIdx.x / BATCH, b = blockIdx.x % BATCH;
    int t = threadIdx.x;
    const float4* y = (const float4*)(pool2 + (size_t)b * 20000);
    const float4* w = (const float4*)(oww + (size_t)cls * 20000);
    float acc = 0.f;
    for (int k = t; k < 5000; k += 256) {
        float4 a = y[k], ww = w[k];
        acc += a.x * ww.x + a.y * ww.y + a.z * ww.z + a.w * ww.w;
    }
    #pragma unroll
    for (int off = 32; off > 0; off >>= 1)
        acc += __shfl_xor(acc, off, 64);
    __shared__ float part[4];
    if ((t & 63) == 0) part[t >> 6] = acc;
    __syncthreads();
    if (t == 0)
        yhat[b * NCLS + cls] = part[0] + part[1] + part[2] + part[3] + ob[cls];
}

extern "C" void kernel_launch(void* const* d_in, const int* in_sizes, int n_in,
                              void* d_out, int out_size, void* d_ws, size_t ws_size,
                              hipStream_t stream)
{
    const float* x   = (const float*)d_in[0];
    const int*   pi0 = (const int*)d_in[1];
    const int*   pi1 = (const int*)d_in[2];
    const float* w1  = (const float*)d_in[3];
    const float* b1  = (const float*)d_in[4];
    const float* w2  = (const float*)d_in[5];
    const float* b2  = (const float*)d_in[6];
    const float* c1w = (const float*)d_in[7];
    const float* c1b = (const float*)d_in[8];
    const float* c2w = (const float*)d_in[9];
    const float* c2b = (const float*)d_in[10];
    const float* oww = (const float*)d_in[11];
    const float* owb = (const float*)d_in[12];
    float* out = (float*)d_out;
    float* ws = (float*)d_ws;

    float* nf     = ws + NF_OFF;
    float* wT1    = ws + WT1_OFF;
    float* wT2    = ws + WT2_OFF;
    float* inv    = ws + INV_OFF;
    float* imgs_p = ws + IMGSP_OFF;
    float* pool1p = ws + POOL1P_OFF;
    float* pool2  = ws + POOL2_OFF;

    k_init <<<2 + (ZERO_N4 + 255) / 256, 256, 0, stream>>>(c1w, c2w, wT1, wT2, imgs_p);
    k_filt <<<1000, 256, 0, stream>>>(x, w1, b1, w2, b2, nf, out + BATCH * NCLS);
    k_pimg <<<256, 256, 0, stream>>>(nf, pi0, pi1, imgs_p);
    k_pmax <<<64, 256, 0, stream>>>(imgs_p, inv);
    k_conv1<<<1280, 256, 0, stream>>>(imgs_p, wT1, c1b, inv, pool1p);
    k_conv2<<<1024, 320, 0, stream>>>(pool1p, wT2, c2b, pool2);
    k_fc   <<<BATCH * NCLS, 256, 0, stream>>>(pool2, oww, owb, out);
}

// Round 8
// 138.937 us; speedup vs baseline: 1.5414x; 1.2527x over previous
//
#include <hip/hip_runtime.h>
#include <hip/hip_bf16.h>

#define N_NODES 16000
#define IN_F 128
#define HID 64
#define BATCH 32
#define NPAIR 128
#define DRES 100
#define NCLS 10

// workspace layout (float offsets)
#define NF_OFF     0
#define WT1_OFF    16000                     // [2 ic][25 tap][16 oc]
#define WT2_OFF    (16000 + 800)             // [16 ic][25 tap][32 oc]
#define INV_OFF    (16000 + 800 + 12800)     // [64] per-(b,c) 1/max
#define IMGSP_OFF  (INV_OFF + 64)            // [32][2][104][104] padded
#define POOL1P_OFF (IMGSP_OFF + 32*2*104*104)   // [32][16][54][56] padded
#define POOL2_OFF  (POOL1P_OFF + 32*16*54*56)   // [32][32][25][25]
#define ZERO_N4    ((32*2*104*104 + 32*16*54*56) / 4)

// k_init block-range constants
#define NZBLK  ((ZERO_N4 + 255) / 256)       // zero blocks
#define NFILT  1000                          // filt blocks (16 nodes each)

// float2 patch element access (compile-time index under full unroll)
#define PV(P, r, c) (((c) & 1) ? P[(r)*3 + ((c)>>1)].y : P[(r)*3 + ((c)>>1)].x)

// ---------------- Kernel I: weight transpose + zero buffers + node-filt MLP ----------------
// bx==0: wT1; bx==1: wT2; bx in [2, 2+NZBLK): zero; bx >= 2+NZBLK: filtration MLP.
__global__ __launch_bounds__(256) void k_init(const float* __restrict__ c1w,
    const float* __restrict__ c2w, float* __restrict__ wT1, float* __restrict__ wT2,
    float* __restrict__ zbase,
    const float* __restrict__ x, const float* __restrict__ w1,
    const float* __restrict__ b1, const float* __restrict__ w2,
    const float* __restrict__ b2, float* __restrict__ nf, float* __restrict__ out_nf)
{
    int bx = blockIdx.x, t = threadIdx.x;
    if (bx == 0) {
        for (int i = t; i < 800; i += 256) {
            int ic = i / 400, tap = (i / 16) % 25, oc = i % 16;
            wT1[i] = c1w[(oc * 2 + ic) * 25 + tap];
        }
        return;
    }
    if (bx == 1) {
        for (int i = t; i < 12800; i += 256) {
            int ic = i / 800, tap = (i / 32) % 25, oc = i % 32;
            wT2[i] = c2w[(oc * 16 + ic) * 25 + tap];
        }
        return;
    }
    if (bx < 2 + NZBLK) {
        int i = (bx - 2) * 256 + t;
        if (i < ZERO_N4) ((float4*)zbase)[i] = make_float4(0.f, 0.f, 0.f, 0.f);
        return;
    }
    // ---- node filtration MLP: 4 nodes per wave ----
    int blk = bx - (2 + NZBLK);
    int wave = t >> 6, lane = t & 63;
    int n0 = blk * 16 + wave * 4;
    if (n0 >= N_NODES) return;
    const float* x0 = x + (size_t)n0 * IN_F;
    float a0 = 0.f, a1 = 0.f, a2 = 0.f, a3 = 0.f;
    #pragma unroll 4
    for (int k = 0; k < IN_F; ++k) {
        float wv = w1[k * HID + lane];
        a0 = fmaf(x0[k], wv, a0);
        a1 = fmaf(x0[k + IN_F], wv, a1);
        a2 = fmaf(x0[k + 2 * IN_F], wv, a2);
        a3 = fmaf(x0[k + 3 * IN_F], wv, a3);
    }
    float bb = b1[lane], w2v = w2[lane];
    float p0 = fmaxf(a0 + bb, 0.f) * w2v;
    float p1 = fmaxf(a1 + bb, 0.f) * w2v;
    float p2 = fmaxf(a2 + bb, 0.f) * w2v;
    float p3 = fmaxf(a3 + bb, 0.f) * w2v;
    #pragma unroll
    for (int off = 32; off > 0; off >>= 1) {
        p0 += __shfl_xor(p0, off, 64);
        p1 += __shfl_xor(p1, off, 64);
        p2 += __shfl_xor(p2, off, 64);
        p3 += __shfl_xor(p3, off, 64);
    }
    if (lane == 0) {
        float bv = b2[0];
        float f0 = 1.f / (1.f + expf(-(p0 + bv)));
        float f1 = 1.f / (1.f + expf(-(p1 + bv)));
        float f2 = 1.f / (1.f + expf(-(p2 + bv)));
        float f3 = 1.f / (1.f + expf(-(p3 + bv)));
        nf[n0] = f0; nf[n0 + 1] = f1; nf[n0 + 2] = f2; nf[n0 + 3] = f3;
        out_nf[n0] = f0; out_nf[n0 + 1] = f1; out_nf[n0 + 2] = f2; out_nf[n0 + 3] = f3;
    }
}

// ---------------- Kernel B: persistence image partial accumulate ----------------
// 256 blocks: (img, quarter). 4 quarter-blocks of an img share g%8 -> same XCD L2.
__global__ __launch_bounds__(256) void k_pimg(const float* __restrict__ nf,
    const int* __restrict__ pi0, const int* __restrict__ pi1,
    float* __restrict__ imgs_p)
{
    int g = blockIdx.x;
    int img = (g & 7) * 8 + ((g >> 3) & 7);
    int q = g >> 6;
    int b = img >> 1, c = img & 1;
    const int* pi = c ? pi1 : pi0;
    __shared__ float sb[32], sp[32];
    int t = threadIdx.x;
    if (t < 32) {
        int p = q * 32 + t;
        int i0 = pi[(b * NPAIR + p) * 2 + 0];
        int i1 = pi[(b * NPAIR + p) * 2 + 1];
        float f0 = nf[i0], f1 = nf[i1];
        sb[t] = f0;
        sp[t] = f1 - f0;
    }
    __syncthreads();
    if (t >= 169) return;
    int ti = t / 13, tj = t % 13;
    float ci[8], cj[8];
    #pragma unroll
    for (int r = 0; r < 8; ++r) {
        ci[r] = (float)(ti + 13 * r) * 0.01f;
        cj[r] = (float)(tj + 13 * r) * 0.01f;
    }
    float acc[8][8];
    #pragma unroll
    for (int r = 0; r < 8; ++r)
        #pragma unroll
        for (int s = 0; s < 8; ++s) acc[r][s] = 0.f;
    for (int p = 0; p < 32; ++p) {
        float bb = sb[p], pp = sp[p];
        float eb[8], ep[8];
        #pragma unroll
        for (int r = 0; r < 8; ++r) { float d = bb - ci[r]; eb[r] = __expf(-d * d); }
        #pragma unroll
        for (int s = 0; s < 8; ++s) { float d = pp - cj[s]; ep[s] = __expf(-d * d); }
        #pragma unroll
        for (int r = 0; r < 8; ++r)
            #pragma unroll
            for (int s = 0; s < 8; ++s)
                acc[r][s] = fmaf(eb[r], ep[s], acc[r][s]);
    }
    float* dst = imgs_p + (size_t)img * 10816 + 2 * 104 + 2;
    #pragma unroll
    for (int r = 0; r < 8; ++r) {
        int i = ti + 13 * r;
        if (i < DRES) {
            #pragma unroll
            for (int s = 0; s < 8; ++s) {
                int j = tj + 13 * s;
                if (j < DRES) atomicAdd(&dst[i * 104 + j], acc[r][s]);
            }
        }
    }
}

// ---------------- Kernel M: per-image max -> inv ----------------
__global__ __launch_bounds__(256) void k_pmax(const float* __restrict__ imgs_p,
    float* __restrict__ inv)
{
    int img = blockIdx.x;
    const float4* src = (const float4*)(imgs_p + (size_t)img * 10816);
    int t = threadIdx.x;
    float m = 0.f;
    for (int k = t; k < 2704; k += 256) {
        float4 v = src[k];
        m = fmaxf(m, fmaxf(fmaxf(v.x, v.y), fmaxf(v.z, v.w)));
    }
    #pragma unroll
    for (int off = 32; off > 0; off >>= 1)
        m = fmaxf(m, __shfl_xor(m, off, 64));
    __shared__ float wm[4];
    if ((t & 63) == 0) wm[t >> 6] = m;
    __syncthreads();
    if (t == 0) {
        float bm = fmaxf(fmaxf(wm[0], wm[1]), fmaxf(wm[2], wm[3]));
        inv[img] = 1.f / bm;
    }
}

// ---------------- Kernel C: conv1 + relu + maxpool2 ----------------
// 1280 blocks: (b, ocg in 4, rowgroup in 10). 250 active threads = 50 ow x 5 rows.
__global__ __launch_bounds__(256) void k_conv1(const float* __restrict__ imgs_p,
    const float* __restrict__ wT1, const float* __restrict__ cb,
    const float* __restrict__ inv, float* __restrict__ pool1p)
{
    int g = blockIdx.x;
    int b = (g & 7) * 4 + ((g >> 3) & 3);
    int ocg = (g >> 5) & 3;
    int rg = g >> 7;
    int t = threadIdx.x;
    if (t >= 250) return;
    int ow = t % 50, oh = rg * 5 + t / 50;

    float2 PA[18], PB[18];
    {
        const float* bs = imgs_p + (size_t)(b * 2 + 0) * 10816 + (2 * oh) * 104 + 2 * ow;
        #pragma unroll
        for (int r = 0; r < 6; ++r) {
            const float* rp = bs + r * 104;
            PA[r * 3 + 0] = *(const float2*)rp;
            PA[r * 3 + 1] = *(const float2*)(rp + 2);
            PA[r * 3 + 2] = *(const float2*)(rp + 4);
        }
        const float* bs1 = bs + 10816;
        #pragma unroll
        for (int r = 0; r < 6; ++r) {
            const float* rp = bs1 + r * 104;
            PB[r * 3 + 0] = *(const float2*)rp;
            PB[r * 3 + 1] = *(const float2*)(rp + 2);
            PB[r * 3 + 2] = *(const float2*)(rp + 4);
        }
    }
    float acc0[4][2][2] = {}, acc1[4][2][2] = {};
    const float* w0 = wT1 + ocg * 4;
    const float* w1r = wT1 + 400 + ocg * 4;
    #pragma unroll
    for (int kh = 0; kh < 5; ++kh)
        #pragma unroll
        for (int kw = 0; kw < 5; ++kw) {
            float4 wa = *(const float4*)(w0 + (kh * 5 + kw) * 16);
            float4 wb = *(const float4*)(w1r + (kh * 5 + kw) * 16);
            #pragma unroll
            for (int j = 0; j < 2; ++j)
                #pragma unroll
                for (int i = 0; i < 2; ++i) {
                    float va = PV(PA, kh + j, kw + i);
                    float vb = PV(PB, kh + j, kw + i);
                    acc0[0][j][i] = fmaf(va, wa.x, acc0[0][j][i]);
                    acc0[1][j][i] = fmaf(va, wa.y, acc0[1][j][i]);
                    acc0[2][j][i] = fmaf(va, wa.z, acc0[2][j][i]);
                    acc0[3][j][i] = fmaf(va, wa.w, acc0[3][j][i]);
                    acc1[0][j][i] = fmaf(vb, wb.x, acc1[0][j][i]);
                    acc1[1][j][i] = fmaf(vb, wb.y, acc1[1][j][i]);
                    acc1[2][j][i] = fmaf(vb, wb.z, acc1[2][j][i]);
                    acc1[3][j][i] = fmaf(vb, wb.w, acc1[3][j][i]);
                }
        }
    float sc0 = inv[b * 2 + 0], sc1 = inv[b * 2 + 1];
    float4 bias4 = *(const float4*)(cb + ocg * 4);
    float bv[4] = {bias4.x, bias4.y, bias4.z, bias4.w};
    #pragma unroll
    for (int o = 0; o < 4; ++o) {
        float v00 = fmaf(sc1, acc1[o][0][0], sc0 * acc0[o][0][0]);
        float v01 = fmaf(sc1, acc1[o][0][1], sc0 * acc0[o][0][1]);
        float v10 = fmaf(sc1, acc1[o][1][0], sc0 * acc0[o][1][0]);
        float v11 = fmaf(sc1, acc1[o][1][1], sc0 * acc0[o][1][1]);
        float m = fmaxf(fmaxf(v00, v01), fmaxf(v10, v11));
        pool1p[((size_t)(b * 16 + ocg * 4 + o) * 54 + oh + 2) * 56 + ow + 2] =
            fmaxf(m + bv[o], 0.f);
    }
}

// ---------------- Kernel D: conv2 + relu + maxpool2 ----------------
// 2560 blocks x 128 threads (2 waves): (b, ocg in 16 [2 oc], rowgroup in 5).
// thread = 2 oc x 1 pooled output; o = rg*125 + t, t < 125 active.
// Small blocks pack many-per-CU (r5/r7 multi-wave blocks would not co-reside):
// 10 blocks/CU = 20 waves/CU at VGPR~68 (7 waves/SIMD cap).
__global__ __launch_bounds__(128) void k_conv2(const float* __restrict__ pool1p,
    const float* __restrict__ wT2, const float* __restrict__ cb,
    float* __restrict__ pool2)
{
    int g = blockIdx.x;
    int b = (g & 7) * 4 + ((g >> 3) & 3);
    int rest = g >> 5;
    int ocg = rest & 15;       // 0..15, 2 oc each
    int rg = rest >> 4;        // 0..4
    int t = threadIdx.x;
    if (t >= 125) return;
    int o = rg * 125 + t;
    int py = o / 25, px = o % 25;
    float acc[2][2][2] = {};
    float2 PA[18], PB[18];

    auto LOADP = [&](float2 (&P)[18], int ic) {
        const float* bs = pool1p + (size_t)(b * 16 + ic) * 3024 + (2 * py) * 56 + 2 * px;
        #pragma unroll
        for (int r = 0; r < 6; ++r) {
            const float* rp = bs + r * 56;
            P[r * 3 + 0] = *(const float2*)rp;
            P[r * 3 + 1] = *(const float2*)(rp + 2);
            P[r * 3 + 2] = *(const float2*)(rp + 4);
        }
    };
    auto FMAIC = [&](float2 (&P)[18], int ic) {
        const float* wrow = wT2 + ic * 800 + ocg * 2;
        #pragma unroll
        for (int kh = 0; kh < 5; ++kh)
            #pragma unroll
            for (int kw = 0; kw < 5; ++kw) {
                float2 wv = *(const float2*)(wrow + (kh * 5 + kw) * 32);
                #pragma unroll
                for (int j = 0; j < 2; ++j)
                    #pragma unroll
                    for (int i = 0; i < 2; ++i) {
                        float v = PV(P, kh + j, kw + i);
                        acc[0][j][i] = fmaf(v, wv.x, acc[0][j][i]);
                        acc[1][j][i] = fmaf(v, wv.y, acc[1][j][i]);
                    }
            }
    };

    LOADP(PA, 0);
    #pragma unroll 1
    for (int ic = 0; ic < 16; ic += 2) {
        LOADP(PB, ic + 1);
        FMAIC(PA, ic);
        if (ic + 2 < 16) LOADP(PA, ic + 2);
        FMAIC(PB, ic + 1);
    }

    float2 bias2 = *(const float2*)(cb + ocg * 2);
    float bv[2] = {bias2.x, bias2.y};
    #pragma unroll
    for (int oo = 0; oo < 2; ++oo) {
        float m = fmaxf(fmaxf(acc[oo][0][0], acc[oo][0][1]),
                        fmaxf(acc[oo][1][0], acc[oo][1][1]));
        pool2[((size_t)(b * 32 + ocg * 2 + oo) * 25 + py) * 25 + px] =
            fmaxf(m + bv[oo], 0.f);
    }
}

// ---------------- Kernel E: final linear (float4) ----------------
__global__ __launch_bounds__(256) void k_fc(const float* __restrict__ pool2,
    const float* __restrict__ oww, const float* __restrict__ ob,
    float* __restrict__ yhat)
{
    int cls = blockIdx.x / BATCH, b = blockIdx.x % BATCH;
    int t = threadIdx.x;
    const float4* y = (const float4*)(pool2 + (size_t)b * 20000);
    const float4* w = (const float4*)(oww + (size_t)cls * 20000);
    float acc = 0.f;
    for (int k = t; k < 5000; k += 256) {
        float4 a = y[k], ww = w[k];
        acc += a.x * ww.x + a.y * ww.y + a.z * ww.z + a.w * ww.w;
    }
    #pragma unroll
    for (int off = 32; off > 0; off >>= 1)
        acc += __shfl_xor(acc, off, 64);
    __shared__ float part[4];
    if ((t & 63) == 0) part[t >> 6] = acc;
    __syncthreads();
    if (t == 0)
        yhat[b * NCLS + cls] = part[0] + part[1] + part[2] + part[3] + ob[cls];
}

extern "C" void kernel_launch(void* const* d_in, const int* in_sizes, int n_in,
                              void* d_out, int out_size, void* d_ws, size_t ws_size,
                              hipStream_t stream)
{
    const float* x   = (const float*)d_in[0];
    const int*   pi0 = (const int*)d_in[1];
    const int*   pi1 = (const int*)d_in[2];
    const float* w1  = (const float*)d_in[3];
    const float* b1  = (const float*)d_in[4];
    const float* w2  = (const float*)d_in[5];
    const float* b2  = (const float*)d_in[6];
    const float* c1w = (const float*)d_in[7];
    const float* c1b = (const float*)d_in[8];
    const float* c2w = (const float*)d_in[9];
    const float* c2b = (const float*)d_in[10];
    const float* oww = (const float*)d_in[11];
    const float* owb = (const float*)d_in[12];
    float* out = (float*)d_out;
    float* ws = (float*)d_ws;

    float* nf     = ws + NF_OFF;
    float* wT1    = ws + WT1_OFF;
    float* wT2    = ws + WT2_OFF;
    float* inv    = ws + INV_OFF;
    float* imgs_p = ws + IMGSP_OFF;
    float* pool1p = ws + POOL1P_OFF;
    float* pool2  = ws + POOL2_OFF;

    k_init <<<2 + NZBLK + NFILT, 256, 0, stream>>>(c1w, c2w, wT1, wT2, imgs_p,
                                                   x, w1, b1, w2, b2, nf,
                                                   out + BATCH * NCLS);
    k_pimg <<<256, 256, 0, stream>>>(nf, pi0, pi1, imgs_p);
    k_pmax <<<64, 256, 0, stream>>>(imgs_p, inv);
    k_conv1<<<1280, 256, 0, stream>>>(imgs_p, wT1, c1b, inv, pool1p);
    k_conv2<<<2560, 128, 0, stream>>>(pool1p, wT2, c2b, pool2);
    k_fc   <<<BATCH * NCLS, 256, 0, stream>>>(pool2, oww, owb, out);
}

// Round 9
// 97.033 us; speedup vs baseline: 2.2070x; 1.4319x over previous
//
#include <hip/hip_runtime.h>
#include <hip/hip_bf16.h>

#define N_NODES 16000
#define IN_F 128
#define HID 64
#define BATCH 32
#define NPAIR 128
#define DRES 100
#define NCLS 10

// workspace layout (float offsets)
#define NF_OFF     0
#define WT1_OFF    16000                     // [2 ic][25 tap][16 oc] fp32
#define WT2B_OFF   (16000 + 800)             // [200 kp][32 oc] packed bf16 pairs (uint)
#define INV_OFF    (16000 + 800 + 12800)     // [64] per-(b,c) 1/max
#define IMGSP_OFF  (INV_OFF + 64)            // [32][2][104][104] padded
#define POOL1P_OFF (IMGSP_OFF + 32*2*104*104)   // [32][16][54][56] padded
#define POOL2_OFF  (POOL1P_OFF + 32*16*54*56)   // [32][32][25][25]
#define ZERO_N4    ((32*2*104*104 + 32*16*54*56) / 4)

#define NZBLK  ((ZERO_N4 + 255) / 256)
#define NFILT  1000

// float2 patch element access (compile-time index under full unroll)
#define PV(P, r, c) (((c) & 1) ? P[(r)*3 + ((c)>>1)].y : P[(r)*3 + ((c)>>1)].x)

typedef short short8 __attribute__((ext_vector_type(8)));
typedef float f32x16 __attribute__((ext_vector_type(16)));

static __device__ __forceinline__ unsigned short f2b(float f) {
    __hip_bfloat16 h = __float2bfloat16(f);
    return *reinterpret_cast<unsigned short*>(&h);
}

// element offset of k=(ic,kh,kw) within inb[16][6][56] (tile row-base 0)
#define COFF(k) (((k)/25)*336 + (((k)%25)/5)*56 + ((k)%25)%5)

// ---------------- Kernel I: weight prep + zero buffers + node-filt MLP ----------------
// bx==0: wT1; bx==1: packed bf16 conv2 weights; [2,2+NZBLK): zero; rest: filt MLP.
__global__ __launch_bounds__(256) void k_init(const float* __restrict__ c1w,
    const float* __restrict__ c2w, float* __restrict__ wT1, unsigned int* __restrict__ wT2b,
    float* __restrict__ zbase,
    const float* __restrict__ x, const float* __restrict__ w1,
    const float* __restrict__ b1, const float* __restrict__ w2,
    const float* __restrict__ b2, float* __restrict__ nf, float* __restrict__ out_nf)
{
    int bx = blockIdx.x, t = threadIdx.x;
    if (bx == 0) {
        for (int i = t; i < 800; i += 256) {
            int ic = i / 400, tap = (i / 16) % 25, oc = i % 16;
            wT1[i] = c1w[(oc * 2 + ic) * 25 + tap];
        }
        return;
    }
    if (bx == 1) {
        // wT2b[kp][oc] = pack(bf16(W[2kp][oc]), bf16(W[2kp+1][oc])), k = ic*25+tap
        for (int i = t; i < 6400; i += 256) {
            int kp = i >> 5, oc = i & 31;
            int k0 = 2 * kp, k1 = k0 + 1;
            float f0 = c2w[(oc * 16 + k0 / 25) * 25 + k0 % 25];
            float f1 = c2w[(oc * 16 + k1 / 25) * 25 + k1 % 25];
            wT2b[i] = (unsigned int)f2b(f0) | ((unsigned int)f2b(f1) << 16);
        }
        return;
    }
    if (bx < 2 + NZBLK) {
        int i = (bx - 2) * 256 + t;
        if (i < ZERO_N4) ((float4*)zbase)[i] = make_float4(0.f, 0.f, 0.f, 0.f);
        return;
    }
    // ---- node filtration MLP: 4 nodes per wave ----
    int blk = bx - (2 + NZBLK);
    int wave = t >> 6, lane = t & 63;
    int n0 = blk * 16 + wave * 4;
    if (n0 >= N_NODES) return;
    const float* x0 = x + (size_t)n0 * IN_F;
    float a0 = 0.f, a1 = 0.f, a2 = 0.f, a3 = 0.f;
    #pragma unroll 4
    for (int k = 0; k < IN_F; ++k) {
        float wv = w1[k * HID + lane];
        a0 = fmaf(x0[k], wv, a0);
        a1 = fmaf(x0[k + IN_F], wv, a1);
        a2 = fmaf(x0[k + 2 * IN_F], wv, a2);
        a3 = fmaf(x0[k + 3 * IN_F], wv, a3);
    }
    float bb = b1[lane], w2v = w2[lane];
    float p0 = fmaxf(a0 + bb, 0.f) * w2v;
    float p1 = fmaxf(a1 + bb, 0.f) * w2v;
    float p2 = fmaxf(a2 + bb, 0.f) * w2v;
    float p3 = fmaxf(a3 + bb, 0.f) * w2v;
    #pragma unroll
    for (int off = 32; off > 0; off >>= 1) {
        p0 += __shfl_xor(p0, off, 64);
        p1 += __shfl_xor(p1, off, 64);
        p2 += __shfl_xor(p2, off, 64);
        p3 += __shfl_xor(p3, off, 64);
    }
    if (lane == 0) {
        float bv = b2[0];
        float f0 = 1.f / (1.f + expf(-(p0 + bv)));
        float f1 = 1.f / (1.f + expf(-(p1 + bv)));
        float f2 = 1.f / (1.f + expf(-(p2 + bv)));
        float f3 = 1.f / (1.f + expf(-(p3 + bv)));
        nf[n0] = f0; nf[n0 + 1] = f1; nf[n0 + 2] = f2; nf[n0 + 3] = f3;
        out_nf[n0] = f0; out_nf[n0 + 1] = f1; out_nf[n0 + 2] = f2; out_nf[n0 + 3] = f3;
    }
}

// ---------------- Kernel B: persistence image partial accumulate ----------------
__global__ __launch_bounds__(256) void k_pimg(const float* __restrict__ nf,
    const int* __restrict__ pi0, const int* __restrict__ pi1,
    float* __restrict__ imgs_p)
{
    int g = blockIdx.x;
    int img = (g & 7) * 8 + ((g >> 3) & 7);
    int q = g >> 6;
    int b = img >> 1, c = img & 1;
    const int* pi = c ? pi1 : pi0;
    __shared__ float sb[32], sp[32];
    int t = threadIdx.x;
    if (t < 32) {
        int p = q * 32 + t;
        int i0 = pi[(b * NPAIR + p) * 2 + 0];
        int i1 = pi[(b * NPAIR + p) * 2 + 1];
        float f0 = nf[i0], f1 = nf[i1];
        sb[t] = f0;
        sp[t] = f1 - f0;
    }
    __syncthreads();
    if (t >= 169) return;
    int ti = t / 13, tj = t % 13;
    float ci[8], cj[8];
    #pragma unroll
    for (int r = 0; r < 8; ++r) {
        ci[r] = (float)(ti + 13 * r) * 0.01f;
        cj[r] = (float)(tj + 13 * r) * 0.01f;
    }
    float acc[8][8];
    #pragma unroll
    for (int r = 0; r < 8; ++r)
        #pragma unroll
        for (int s = 0; s < 8; ++s) acc[r][s] = 0.f;
    for (int p = 0; p < 32; ++p) {
        float bb = sb[p], pp = sp[p];
        float eb[8], ep[8];
        #pragma unroll
        for (int r = 0; r < 8; ++r) { float d = bb - ci[r]; eb[r] = __expf(-d * d); }
        #pragma unroll
        for (int s = 0; s < 8; ++s) { float d = pp - cj[s]; ep[s] = __expf(-d * d); }
        #pragma unroll
        for (int r = 0; r < 8; ++r)
            #pragma unroll
            for (int s = 0; s < 8; ++s)
                acc[r][s] = fmaf(eb[r], ep[s], acc[r][s]);
    }
    float* dst = imgs_p + (size_t)img * 10816 + 2 * 104 + 2;
    #pragma unroll
    for (int r = 0; r < 8; ++r) {
        int i = ti + 13 * r;
        if (i < DRES) {
            #pragma unroll
            for (int s = 0; s < 8; ++s) {
                int j = tj + 13 * s;
                if (j < DRES) atomicAdd(&dst[i * 104 + j], acc[r][s]);
            }
        }
    }
}

// ---------------- Kernel M: per-image max -> inv ----------------
__global__ __launch_bounds__(256) void k_pmax(const float* __restrict__ imgs_p,
    float* __restrict__ inv)
{
    int img = blockIdx.x;
    const float4* src = (const float4*)(imgs_p + (size_t)img * 10816);
    int t = threadIdx.x;
    float m = 0.f;
    for (int k = t; k < 2704; k += 256) {
        float4 v = src[k];
        m = fmaxf(m, fmaxf(fmaxf(v.x, v.y), fmaxf(v.z, v.w)));
    }
    #pragma unroll
    for (int off = 32; off > 0; off >>= 1)
        m = fmaxf(m, __shfl_xor(m, off, 64));
    __shared__ float wm[4];
    if ((t & 63) == 0) wm[t >> 6] = m;
    __syncthreads();
    if (t == 0) {
        float bm = fmaxf(fmaxf(wm[0], wm[1]), fmaxf(wm[2], wm[3]));
        inv[img] = 1.f / bm;
    }
}

// ---------------- Kernel C: conv1 + relu + maxpool2 (VALU) ----------------
__global__ __launch_bounds__(256) void k_conv1(const float* __restrict__ imgs_p,
    const float* __restrict__ wT1, const float* __restrict__ cb,
    const float* __restrict__ inv, float* __restrict__ pool1p)
{
    int g = blockIdx.x;
    int b = (g & 7) * 4 + ((g >> 3) & 3);
    int ocg = (g >> 5) & 3;
    int rg = g >> 7;
    int t = threadIdx.x;
    if (t >= 250) return;
    int ow = t % 50, oh = rg * 5 + t / 50;

    float2 PA[18], PB[18];
    {
        const float* bs = imgs_p + (size_t)(b * 2 + 0) * 10816 + (2 * oh) * 104 + 2 * ow;
        #pragma unroll
        for (int r = 0; r < 6; ++r) {
            const float* rp = bs + r * 104;
            PA[r * 3 + 0] = *(const float2*)rp;
            PA[r * 3 + 1] = *(const float2*)(rp + 2);
            PA[r * 3 + 2] = *(const float2*)(rp + 4);
        }
        const float* bs1 = bs + 10816;
        #pragma unroll
        for (int r = 0; r < 6; ++r) {
            const float* rp = bs1 + r * 104;
            PB[r * 3 + 0] = *(const float2*)rp;
            PB[r * 3 + 1] = *(const float2*)(rp + 2);
            PB[r * 3 + 2] = *(const float2*)(rp + 4);
        }
    }
    float acc0[4][2][2] = {}, acc1[4][2][2] = {};
    const float* w0 = wT1 + ocg * 4;
    const float* w1r = wT1 + 400 + ocg * 4;
    #pragma unroll
    for (int kh = 0; kh < 5; ++kh)
        #pragma unroll
        for (int kw = 0; kw < 5; ++kw) {
            float4 wa = *(const float4*)(w0 + (kh * 5 + kw) * 16);
            float4 wb = *(const float4*)(w1r + (kh * 5 + kw) * 16);
            #pragma unroll
            for (int j = 0; j < 2; ++j)
                #pragma unroll
                for (int i = 0; i < 2; ++i) {
                    float va = PV(PA, kh + j, kw + i);
                    float vb = PV(PB, kh + j, kw + i);
                    acc0[0][j][i] = fmaf(va, wa.x, acc0[0][j][i]);
                    acc0[1][j][i] = fmaf(va, wa.y, acc0[1][j][i]);
                    acc0[2][j][i] = fmaf(va, wa.z, acc0[2][j][i]);
                    acc0[3][j][i] = fmaf(va, wa.w, acc0[3][j][i]);
                    acc1[0][j][i] = fmaf(vb, wb.x, acc1[0][j][i]);
                    acc1[1][j][i] = fmaf(vb, wb.y, acc1[1][j][i]);
                    acc1[2][j][i] = fmaf(vb, wb.z, acc1[2][j][i]);
                    acc1[3][j][i] = fmaf(vb, wb.w, acc1[3][j][i]);
                }
        }
    float sc0 = inv[b * 2 + 0], sc1 = inv[b * 2 + 1];
    float4 bias4 = *(const float4*)(cb + ocg * 4);
    float bv[4] = {bias4.x, bias4.y, bias4.z, bias4.w};
    #pragma unroll
    for (int o = 0; o < 4; ++o) {
        float v00 = fmaf(sc1, acc1[o][0][0], sc0 * acc0[o][0][0]);
        float v01 = fmaf(sc1, acc1[o][0][1], sc0 * acc0[o][0][1]);
        float v10 = fmaf(sc1, acc1[o][1][0], sc0 * acc0[o][1][0]);
        float v11 = fmaf(sc1, acc1[o][1][1], sc0 * acc0[o][1][1]);
        float m = fmaxf(fmaxf(v00, v01), fmaxf(v10, v11));
        pool1p[((size_t)(b * 16 + ocg * 4 + o) * 54 + oh + 2) * 56 + ow + 2] =
            fmaxf(m + bv[o], 0.f);
    }
}

// ---------------- Kernel D: conv2 via MFMA implicit GEMM ----------------
// D[s x oc] = Im^T[s x k] . W[k x oc], K=400 = 25 steps of 16.
// Block=(b,py): 128 thr = 2 waves (h = spatial col-half). Wave holds two C-tiles:
// accA (conv row 2py) / accB (2py+1); pooling collapses in-register.
// A frag: lane supplies Im[m=lane&31][k=8*(lane>>5)+e]; B frag: W[k][oc=lane&31]
// from pre-packed wT2b[kp][oc] (L1-resident). C/D: m=(r&3)+8*(r>>2)+4*(lane>>5).
__global__ __launch_bounds__(128) void k_conv2(const float* __restrict__ pool1p,
    const unsigned int* __restrict__ wg, const float* __restrict__ cb2,
    float* __restrict__ pool2)
{
    int g = blockIdx.x;
    int b = (g & 7) * 4 + ((g >> 3) & 3);
    int py = g >> 5;
    int t = threadIdx.x;

    __shared__ unsigned short inb[5376];  // [16 ic][6 rows][56 cols] bf16
    {
        const float* src = pool1p + (size_t)b * 48384 + (2 * py) * 56;
        unsigned int* inb32 = (unsigned int*)inb;
        for (int i = t; i < 1344; i += 128) {
            int ic = i / 84, rem = i % 84;
            int r = rem / 14, c4 = rem % 14;
            float4 v = *(const float4*)(src + ic * 3024 + r * 56 + c4 * 4);
            inb32[i * 2 + 0] = (unsigned int)f2b(v.x) | ((unsigned int)f2b(v.y) << 16);
            inb32[i * 2 + 1] = (unsigned int)f2b(v.z) | ((unsigned int)f2b(v.w) << 16);
        }
    }
    __syncthreads();

    int lane = t & 63;
    int h = t >> 6;             // wave: spatial col-half
    int hh = lane >> 5;         // k-half within fragment
    int sm = lane & 31;         // A row (spatial) == B col (oc)
    int cb = h * 32 + sm; if (cb > 49) cb = 49;   // clamp dead cols (discarded later)
    int cbA = cb, cbB = cb + 56;
    int oc = sm;
    int wbase = hh * 128 + oc;

    f32x16 accA = {0.f,0.f,0.f,0.f,0.f,0.f,0.f,0.f,0.f,0.f,0.f,0.f,0.f,0.f,0.f,0.f};
    f32x16 accB = {0.f,0.f,0.f,0.f,0.f,0.f,0.f,0.f,0.f,0.f,0.f,0.f,0.f,0.f,0.f,0.f};

    #pragma unroll
    for (int s = 0; s < 25; ++s) {
        // B fragment (weights): 4 coalesced dword loads, pairs pre-packed
        union { short8 v; unsigned int u[4]; } bw;
        bw.u[0] = wg[wbase + s * 256 + 0];
        bw.u[1] = wg[wbase + s * 256 + 32];
        bw.u[2] = wg[wbase + s * 256 + 64];
        bw.u[3] = wg[wbase + s * 256 + 96];
        // A fragments (im2col gather from LDS, compile-time offsets per half)
        unsigned short ua[8], ub[8];
        #pragma unroll
        for (int e = 0; e < 8; ++e) {
            int o = hh ? COFF(16 * s + 8 + e) : COFF(16 * s + e);
            ua[e] = inb[cbA + o];
            ub[e] = inb[cbB + o];
        }
        union { short8 v; unsigned int u[4]; } aA, aB;
        #pragma unroll
        for (int r = 0; r < 4; ++r) {
            aA.u[r] = (unsigned int)ua[2 * r] | ((unsigned int)ua[2 * r + 1] << 16);
            aB.u[r] = (unsigned int)ub[2 * r] | ((unsigned int)ub[2 * r + 1] << 16);
        }
        accA = __builtin_amdgcn_mfma_f32_32x32x16_bf16(aA.v, bw.v, accA, 0, 0, 0);
        accB = __builtin_amdgcn_mfma_f32_32x32x16_bf16(aB.v, bw.v, accB, 0, 0, 0);
    }

    float bias = cb2[oc];
    float* dst = pool2 + ((size_t)(b * 32 + oc) * 25 + py) * 25;
    #pragma unroll
    for (int q = 0; q < 4; ++q) {
        // regs 4q..4q+3 -> conv cols ow = h*32 + 8q + 4*hh + {0,1,2,3}
        float m0 = fmaxf(fmaxf(accA[4 * q + 0], accB[4 * q + 0]),
                         fmaxf(accA[4 * q + 1], accB[4 * q + 1]));
        float m1 = fmaxf(fmaxf(accA[4 * q + 2], accB[4 * q + 2]),
                         fmaxf(accA[4 * q + 3], accB[4 * q + 3]));
        int px0 = h * 16 + 4 * q + 2 * hh;
        if (px0 < 25) dst[px0] = fmaxf(m0 + bias, 0.f);
        if (px0 + 1 < 25) dst[px0 + 1] = fmaxf(m1 + bias, 0.f);
    }
}

// ---------------- Kernel E: final linear (float4) ----------------
__global__ __launch_bounds__(256) void k_fc(const float* __restrict__ pool2,
    const float* __restrict__ oww, const float* __restrict__ ob,
    float* __restrict__ yhat)
{
    int cls = blockIdx.x / BATCH, b = blockIdx.x % BATCH;
    int t = threadIdx.x;
    const float4* y = (const float4*)(pool2 + (size_t)b * 20000);
    const float4* w = (const float4*)(oww + (size_t)cls * 20000);
    float acc = 0.f;
    for (int k = t; k < 5000; k += 256) {
        float4 a = y[k], ww = w[k];
        acc += a.x * ww.x + a.y * ww.y + a.z * ww.z + a.w * ww.w;
    }
    #pragma unroll
    for (int off = 32; off > 0; off >>= 1)
        acc += __shfl_xor(acc, off, 64);
    __shared__ float part[4];
    if ((t & 63) == 0) part[t >> 6] = acc;
    __syncthreads();
    if (t == 0)
        yhat[b * NCLS + cls] = part[0] + part[1] + part[2] + part[3] + ob[cls];
}

extern "C" void kernel_launch(void* const* d_in, const int* in_sizes, int n_in,
                              void* d_out, int out_size, void* d_ws, size_t ws_size,
                              hipStream_t stream)
{
    const float* x   = (const float*)d_in[0];
    const int*   pi0 = (const int*)d_in[1];
    const int*   pi1 = (const int*)d_in[2];
    const float* w1  = (const float*)d_in[3];
    const float* b1  = (const float*)d_in[4];
    const float* w2  = (const float*)d_in[5];
    const float* b2  = (const float*)d_in[6];
    const float* c1w = (const float*)d_in[7];
    const float* c1b = (const float*)d_in[8];
    const float* c2w = (const float*)d_in[9];
    const float* c2b = (const float*)d_in[10];
    const float* oww = (const float*)d_in[11];
    const float* owb = (const float*)d_in[12];
    float* out = (float*)d_out;
    float* ws = (float*)d_ws;

    float*        nf     = ws + NF_OFF;
    float*        wT1    = ws + WT1_OFF;
    unsigned int* wT2b   = (unsigned int*)(ws + WT2B_OFF);
    float*        inv    = ws + INV_OFF;
    float*        imgs_p = ws + IMGSP_OFF;
    float*        pool1p = ws + POOL1P_OFF;
    float*        pool2  = ws + POOL2_OFF;

    k_init <<<2 + NZBLK + NFILT, 256, 0, stream>>>(c1w, c2w, wT1, wT2b, imgs_p,
                                                   x, w1, b1, w2, b2, nf,
                                                   out + BATCH * NCLS);
    k_pimg <<<256, 256, 0, stream>>>(nf, pi0, pi1, imgs_p);
    k_pmax <<<64, 256, 0, stream>>>(imgs_p, inv);
    k_conv1<<<1280, 256, 0, stream>>>(imgs_p, wT1, c1b, inv, pool1p);
    k_conv2<<<800, 128, 0, stream>>>(pool1p, wT2b, c2b, pool2);
    k_fc   <<<BATCH * NCLS, 256, 0, stream>>>(pool2, oww, owb, out);
}